// Round 9
// baseline (124.779 us; speedup 1.0000x reference)
//
#include <hip/hip_runtime.h>
#include <hip/hip_bf16.h>

// Problem constants: B=4, C=256, N=4096, G=8, NH=8, HD=32, M=512
#define Bb 4
#define Cc 256
#define Nn 4096
#define Gg 8
#define NHh 8
#define HDd 32
#define Mm 512

typedef __bf16 bf16_t;
typedef __bf16 bf16x2 __attribute__((ext_vector_type(2)));
typedef __bf16 bf16x4 __attribute__((ext_vector_type(4)));
typedef __bf16 bf16x8 __attribute__((ext_vector_type(8)));
typedef float f32x4 __attribute__((ext_vector_type(4)));

// hd^-0.5 * log2(e): folded into Q at the QKV epilogue so attn's
// exponent is plain exp2(S).
#define LSCALE (0.17677669529663687f * 1.44269504088896340f)

__device__ __forceinline__ void load_lds16(const bf16_t* g, bf16_t* l) {
  __builtin_amdgcn_global_load_lds(
      (const __attribute__((address_space(1))) void*)g,
      (__attribute__((address_space(3))) void*)l, 16, 0, 0);
}

// ------------------------------------- prep: transpose+cast x, cast weights
// blocks [0,1024): 64x64 transpose tiles of x -> xT [B][N][C] bf16
//   f32x4 global reads (16B/lane) + bf16x8 stores (16B/lane);
//   LDS stride 65 words keeps both phases <=2-way bank aliasing (free).
// blocks [1024,1792): weight casts
__global__ __launch_bounds__(256) void prep_kernel(
    const float* __restrict__ x, bf16_t* __restrict__ xT,
    const float* __restrict__ wqkv, const float* __restrict__ wproj,
    bf16_t* __restrict__ wq_b, bf16_t* __restrict__ wp_b) {
  int bid = blockIdx.x, tid = threadIdx.x;
  if (bid >= 1024) {
    int i = (bid - 1024) * 256 + tid;
    wq_b[i] = (bf16_t)wqkv[i];
    if (i < Cc * Cc) wp_b[i] = (bf16_t)wproj[i];
    return;
  }
  __shared__ float t[64][65];
  int b = bid >> 8, c0 = ((bid >> 6) & 3) * 64, n0 = (bid & 63) * 64;
  const float* xp = x + ((long long)b * Cc + c0) * Nn + n0;
#pragma unroll
  for (int it = 0; it < 4; ++it) {
    int idx = it * 256 + tid;          // [0,1024)
    int r = idx >> 4, col = (idx & 15) * 4;   // r = c offset, col = n offset
    f32x4 v = *(const f32x4*)&xp[(long long)r * Nn + col];
    t[r][col] = v[0];
    t[r][col + 1] = v[1];
    t[r][col + 2] = v[2];
    t[r][col + 3] = v[3];
  }
  __syncthreads();
  bf16_t* op = xT + ((long long)b * Nn + n0) * Cc + c0;
#pragma unroll
  for (int it = 0; it < 2; ++it) {
    int idx = it * 256 + tid;          // [0,512)
    int n = idx >> 3, cg = (idx & 7) * 8;     // n = n offset, cg = c offset
    bf16x8 w;
#pragma unroll
    for (int j = 0; j < 8; ++j) w[j] = (bf16_t)t[cg + j][n];
    *(bf16x8*)&op[(long long)n * Cc + cg] = w;
  }
}

// --------------------------------------------- QKV GEMM (merged QK + V^T)
// blocks [0,512):  QK  C[n][i]=sum_c xT[n][c]*Wqk[i][c] -> Qh/Kh [head][m][d]
//                  (Q scaled by LSCALE at the epilogue)
// blocks [512,768): V^T C[i][n]=sum_c Wv[i][c]*xT[b][n][c] -> Vh [head][d][m]
__global__ __launch_bounds__(256) void qkv_gemm_kernel(
    const bf16_t* __restrict__ xT, const bf16_t* __restrict__ wqb,
    bf16_t* __restrict__ Qh, bf16_t* __restrict__ Kh, bf16_t* __restrict__ Vh) {
  __shared__ bf16_t As[128 * 32];
  __shared__ bf16_t Bs[128 * 32];
  int bid = blockIdx.x;
  int tid = threadIdx.x, lane = tid & 63, wid = tid >> 6;
  int quad = lane >> 4, l16 = lane & 15;
  bool isQK = bid < 512;
  const bf16_t *A, *Bt;
  int m0, n0, z = 0;
  if (isQK) {
    m0 = (bid >> 2) * 128;           // 16384 rows (b,n)
    n0 = (bid & 3) * 128;            // 512 cols (qk feature)
    A = xT;
    Bt = wqb;
  } else {
    int vb = bid - 512;              // z(4) * y(2) * x(32)
    z = vb >> 6;
    int rem = vb & 63;
    m0 = (rem >> 5) * 128;           // 256 rows (v feature)
    n0 = (rem & 31) * 128;           // 4096 cols (n)
    A = wqb + 512 * Cc;              // Wv
    Bt = xT + (long long)z * Nn * Cc;
  }
  int wm = (wid >> 1) * 64, wn = (wid & 1) * 64;

  f32x4 acc[4][4];
#pragma unroll
  for (int i = 0; i < 4; ++i)
#pragma unroll
    for (int j = 0; j < 4; ++j) acc[i][j] = (f32x4){0.f, 0.f, 0.f, 0.f};

  int scol = (lane & 3) * 8;
  for (int k0 = 0; k0 < Cc; k0 += 32) {
    __syncthreads();
#pragma unroll
    for (int r = 0; r < 2; ++r) {
      int chunk = wid * 2 + r;
      int row = chunk * 16 + (lane >> 2);
      load_lds16(&A[(long long)(m0 + row) * Cc + k0 + scol], &As[chunk * 512]);
      load_lds16(&Bt[(long long)(n0 + row) * Cc + k0 + scol], &Bs[chunk * 512]);
    }
    __syncthreads();
    bf16x8 a[4], b[4];
#pragma unroll
    for (int i = 0; i < 4; ++i)
      a[i] = *(const bf16x8*)&As[(wm + i * 16 + l16) * 32 + quad * 8];
#pragma unroll
    for (int j = 0; j < 4; ++j)
      b[j] = *(const bf16x8*)&Bs[(wn + j * 16 + l16) * 32 + quad * 8];
#pragma unroll
    for (int i = 0; i < 4; ++i)
#pragma unroll
      for (int j = 0; j < 4; ++j)
        acc[i][j] = __builtin_amdgcn_mfma_f32_16x16x32_bf16(a[i], b[j], acc[i][j], 0, 0, 0);
  }

#pragma unroll
  for (int i = 0; i < 4; ++i) {
#pragma unroll
    for (int j = 0; j < 4; ++j) {
      int col = n0 + wn + j * 16 + l16;
#pragma unroll
      for (int r = 0; r < 4; ++r) {
        int row = m0 + wm + i * 16 + quad * 4 + r;
        float v = acc[i][j][r];
        if (isQK) {
          int bb = row >> 12, gg = (row >> 9) & 7, m = row & 511;
          int hh = (col >> 5) & 7, d = col & 31;
          long long hb = (long long)((bb << 6) | (gg << 3) | hh) * (Mm * HDd);
          if (col < 256)
            Qh[hb + m * HDd + d] = (bf16_t)(v * LSCALE);
          else
            Kh[hb + m * HDd + d] = (bf16_t)v;
        } else {
          int hh = row >> 5, d = row & 31, gg = col >> 9, m = col & 511;
          long long hb = (long long)((z << 6) | (gg << 3) | hh) * (Mm * HDd);
          Vh[hb + d * Mm + m] = (bf16_t)v;
        }
      }
    }
  }
}

// ------------------------------------------------------------------ attention
// Qh/Kh: [head][m][d] bf16 (head = b*64+g*8+h; Q pre-scaled by LSCALE)
// Vh:    [head][d][m] bf16 (32x512 slices)
// Oa:    [B*N][256]   bf16
// Grid: 256 blocks = one HEAD per block (R9), 512 threads / 8 waves.
//
// R9: one block per head — K/V staged once (not twice), prologue amortized,
// and with ~100 live VGPRs the 66KB-LDS kernel can reach 2 blocks/CU =
// 16 waves/CU (was 8) for the latency-bound inner loop. Per-wave work is
// unchanged: 64 Q rows = 2 dual-m-tile K-sweeps. S^T formulation (C-layout
// of S^T = B-operand layout of P^T, no P LDS round-trip), two m-tiles share
// every kf/vf load, no-max softmax (validated R5-R8), scale folded into Q.
__global__ __launch_bounds__(512, 2) void attn_kernel(
    const bf16_t* __restrict__ Qh, const bf16_t* __restrict__ Kh,
    const bf16_t* __restrict__ Vh, bf16_t* __restrict__ Oa) {
  __shared__ bf16_t Ks[512 * 32];      // verbatim K slice copy
  __shared__ bf16_t Vs[32 * 520];      // rows padded to 520 (b128-aligned)
  int head = blockIdx.x;
  int h = head & 7, g = (head >> 3) & 7, b = head >> 6;
  int tid = threadIdx.x, lane = tid & 63, wid = tid >> 6;   // wid in [0,8)
  int quad = lane >> 4, l16 = lane & 15;

  const bf16_t* Kg = Kh + (long long)head * (Mm * HDd);
  const bf16_t* Vg = Vh + (long long)head * (Mm * HDd);
  const bf16_t* Qg = Qh + (long long)head * (Mm * HDd);

  // Stage K (verbatim, 512 bf16 per instruction) and V (1KB rows, stride 520).
#pragma unroll
  for (int it = 0; it < 4; ++it) {
    int chunk = wid * 4 + it;
    load_lds16(&Kg[chunk * 512 + lane * 8], &Ks[chunk * 512]);
  }
#pragma unroll
  for (int it = 0; it < 4; ++it) {
    int d = wid * 4 + it;
    load_lds16(&Vg[d * Mm + lane * 8], &Vs[d * 520]);
  }
  __syncthreads();

  // Permuted K-row gather: tile0 rows 8q+r, tile1 rows 8q+4+r (q=l16>>2,r=l16&3)
  int rp0 = ((l16 >> 2) << 3) | (l16 & 3);
  const bf16_t* Kp0 = &Ks[rp0 * HDd + quad * 8];        // +nb*HDd per chunk
  const bf16_t* Kp1 = Kp0 + 4 * HDd;
  const bf16_t* VsL = &Vs[l16 * 520 + quad * 8];
  const bf16_t* VsH = &Vs[(16 + l16) * 520 + quad * 8];
  const f32x4 zero = (f32x4){0.f, 0.f, 0.f, 0.f};

#pragma unroll 1
  for (int t = 0; t < 2; ++t) {
    int m0 = wid * 64 + t * 32;  // two m-tiles: m0 and m0+16 (rows 0..511)
    bf16x8 qa = *(const bf16x8*)&Qg[(m0 + l16) * HDd + quad * 8];
    bf16x8 qb = *(const bf16x8*)&Qg[(m0 + 16 + l16) * HDd + quad * 8];

    float sma = 0.f, smb = 0.f;
    f32x4 oLa = zero, oHa = zero, oLb = zero, oHb = zero;

#pragma unroll 4
    for (int c = 0; c < 16; ++c) {       // 32 K-rows per chunk
      int nb = c * 32;
      bf16x8 kf0 = *(const bf16x8*)&Kp0[nb * HDd];
      bf16x8 kf1 = *(const bf16x8*)&Kp1[nb * HDd];
      f32x4 sa0 = __builtin_amdgcn_mfma_f32_16x16x32_bf16(kf0, qa, zero, 0, 0, 0);
      f32x4 sa1 = __builtin_amdgcn_mfma_f32_16x16x32_bf16(kf1, qa, zero, 0, 0, 0);
      f32x4 sb0 = __builtin_amdgcn_mfma_f32_16x16x32_bf16(kf0, qb, zero, 0, 0, 0);
      f32x4 sb1 = __builtin_amdgcn_mfma_f32_16x16x32_bf16(kf1, qb, zero, 0, 0, 0);
      bf16x8 pa, pb;
#pragma unroll
      for (int r = 0; r < 4; ++r) {
        float e0 = __builtin_exp2f(sa0[r]);
        float e1 = __builtin_exp2f(sa1[r]);
        sma += e0 + e1;
        pa[r] = (bf16_t)e0;
        pa[4 + r] = (bf16_t)e1;
        float f0 = __builtin_exp2f(sb0[r]);
        float f1 = __builtin_exp2f(sb1[r]);
        smb += f0 + f1;
        pb[r] = (bf16_t)f0;
        pb[4 + r] = (bf16_t)f1;
      }
      bf16x8 vL = *(const bf16x8*)&VsL[nb];
      bf16x8 vH = *(const bf16x8*)&VsH[nb];
      oLa = __builtin_amdgcn_mfma_f32_16x16x32_bf16(vL, pa, oLa, 0, 0, 0);
      oHa = __builtin_amdgcn_mfma_f32_16x16x32_bf16(vH, pa, oHa, 0, 0, 0);
      oLb = __builtin_amdgcn_mfma_f32_16x16x32_bf16(vL, pb, oLb, 0, 0, 0);
      oHb = __builtin_amdgcn_mfma_f32_16x16x32_bf16(vH, pb, oHb, 0, 0, 0);
    }

    // sum over n: reduce quad partials (m = l16 is lane-resident)
    sma += __shfl_xor(sma, 16, 64);
    sma += __shfl_xor(sma, 32, 64);
    smb += __shfl_xor(smb, 16, 64);
    smb += __shfl_xor(smb, 32, 64);
    float inva = 1.f / sma, invb = 1.f / smb;

    // O^T in C-layout: lane holds O^T[d=quad*4+r (+0/16)][m=l16]
    long long orowa =
        ((long long)(b * Nn + g * Mm + m0 + l16)) * Cc + h * HDd;
    long long orowb = orowa + 16 * Cc;
    bf16x4 wLa, wHa, wLb, wHb;
#pragma unroll
    for (int r = 0; r < 4; ++r) {
      wLa[r] = (bf16_t)(oLa[r] * inva);
      wHa[r] = (bf16_t)(oHa[r] * inva);
      wLb[r] = (bf16_t)(oLb[r] * invb);
      wHb[r] = (bf16_t)(oHb[r] * invb);
    }
    *(bf16x4*)&Oa[orowa + quad * 4] = wLa;
    *(bf16x4*)&Oa[orowa + 16 + quad * 4] = wHa;
    *(bf16x4*)&Oa[orowb + quad * 4] = wLb;
    *(bf16x4*)&Oa[orowb + 16 + quad * 4] = wHb;
  }
}

// ----------------------------------------------------------------- proj GEMM
// out[b][i][n] = sum_c Wp[i][c]*Oa[b*N+n][c] + bias[i]; z-batched over b.
__global__ __launch_bounds__(256) void proj_kernel(
    const bf16_t* __restrict__ Wp, const bf16_t* __restrict__ Oa,
    float* __restrict__ out, const float* __restrict__ bias) {
  __shared__ bf16_t As[128 * 32];
  __shared__ bf16_t Bs[128 * 32];
  int tid = threadIdx.x, lane = tid & 63, wid = tid >> 6;
  int quad = lane >> 4, l16 = lane & 15;
  int z = blockIdx.z;
  const bf16_t* Bt = Oa + (long long)z * Nn * Cc;
  int m0 = blockIdx.y * 128, n0 = blockIdx.x * 128;
  int wm = (wid >> 1) * 64, wn = (wid & 1) * 64;

  f32x4 acc[4][4];
#pragma unroll
  for (int i = 0; i < 4; ++i)
#pragma unroll
    for (int j = 0; j < 4; ++j) acc[i][j] = (f32x4){0.f, 0.f, 0.f, 0.f};

  int scol = (lane & 3) * 8;
  for (int k0 = 0; k0 < Cc; k0 += 32) {
    __syncthreads();
#pragma unroll
    for (int r = 0; r < 2; ++r) {
      int chunk = wid * 2 + r;
      int row = chunk * 16 + (lane >> 2);
      load_lds16(&Wp[(long long)(m0 + row) * Cc + k0 + scol], &As[chunk * 512]);
      load_lds16(&Bt[(long long)(n0 + row) * Cc + k0 + scol], &Bs[chunk * 512]);
    }
    __syncthreads();
    bf16x8 a[4], b[4];
#pragma unroll
    for (int i = 0; i < 4; ++i)
      a[i] = *(const bf16x8*)&As[(wm + i * 16 + l16) * 32 + quad * 8];
#pragma unroll
    for (int j = 0; j < 4; ++j)
      b[j] = *(const bf16x8*)&Bs[(wn + j * 16 + l16) * 32 + quad * 8];
#pragma unroll
    for (int i = 0; i < 4; ++i)
#pragma unroll
      for (int j = 0; j < 4; ++j)
        acc[i][j] = __builtin_amdgcn_mfma_f32_16x16x32_bf16(a[i], b[j], acc[i][j], 0, 0, 0);
  }

#pragma unroll
  for (int i = 0; i < 4; ++i) {
#pragma unroll
    for (int j = 0; j < 4; ++j) {
      int col = n0 + wn + j * 16 + l16;
#pragma unroll
      for (int r = 0; r < 4; ++r) {
        int row = m0 + wm + i * 16 + quad * 4 + r;
        out[(long long)z * (Cc * Nn) + (long long)row * Nn + col] =
            acc[i][j][r] + bias[row];
      }
    }
  }
}

// ------------------------------------------------------------------- launcher
extern "C" void kernel_launch(void* const* d_in, const int* in_sizes, int n_in,
                              void* d_out, int out_size, void* d_ws, size_t ws_size,
                              hipStream_t stream) {
  (void)in_sizes; (void)n_in; (void)out_size; (void)ws_size;
  const float* x = (const float*)d_in[0];
  const float* w_qkv = (const float*)d_in[1];
  const float* w_proj = (const float*)d_in[2];
  const float* b_proj = (const float*)d_in[3];
  float* out = (float*)d_out;

  char* ws = (char*)d_ws;
  bf16_t* xT  = (bf16_t*)(ws);                 // [B][N][C]     8,388,608 B
  bf16_t* wqb = (bf16_t*)(ws + 8388608);       // [768][256]      393,216 B
  bf16_t* wpb = (bf16_t*)(ws + 8781824);       // [256][256]      131,072 B
  bf16_t* Qh  = (bf16_t*)(ws + 8912896);       // [256][512][32] 8,388,608 B
  bf16_t* Kh  = (bf16_t*)(ws + 17301504);      // [256][512][32] 8,388,608 B
  bf16_t* Vh  = (bf16_t*)(ws + 25690112);      // [256][32][512] 8,388,608 B
  bf16_t* Oa  = (bf16_t*)(ws + 34078720);      // [B*N][256]     8,388,608 B

  prep_kernel<<<1792, 256, 0, stream>>>(x, xT, w_qkv, w_proj, wqb, wpb);
  qkv_gemm_kernel<<<768, 256, 0, stream>>>(xT, wqb, Qh, Kh, Vh);
  attn_kernel<<<256, 512, 0, stream>>>(Qh, Kh, Vh, Oa);
  proj_kernel<<<dim3(32, 2, 4), 256, 0, stream>>>(wpb, Oa, out, b_proj);
}